// Round 10
// baseline (247.489 us; speedup 1.0000x reference)
//
#include <hip/hip_runtime.h>
#include <math.h>

// Problem constants (B, N, TF, DM) = (16, 4096, 512, 1024)
#define B_DIM 16
#define N_SEQ 4096
#define TF_DIM 512
#define DM_DIM 1024
#define CHUNK 128
#define NCHUNK (N_SEQ / CHUNK)   // 32
#define NT 16                    // K-tiles of BK=64 (K=1024)

typedef __attribute__((ext_vector_type(4))) float f32x4;
typedef __attribute__((ext_vector_type(8))) short bf16x8;
typedef unsigned short u16;
typedef unsigned int u32;

__device__ __forceinline__ u16 f2bf(float f) {
    u32 u = __builtin_bit_cast(u32, f);
    u += 0x7fffu + ((u >> 16) & 1u);
    return (u16)(u >> 16);
}

__device__ __forceinline__ u32 cvtpk(float lo, float hi) {
    u32 r;
    asm("v_cvt_pk_bf16_f32 %0, %1, %2" : "=v"(r) : "v"(lo), "v"(hi));
    return r;
}

__device__ __forceinline__ void gload16(const u16* g, u16* l) {
    __builtin_amdgcn_global_load_lds(
        (const __attribute__((address_space(1))) void*)g,
        (__attribute__((address_space(3))) void*)l, 16, 0, 0);
}

#define BAR() __builtin_amdgcn_s_barrier()
// one drain per K-tile (4 phases) — staging was issued at phases 0-1, so by
// here it has had >=2 MFMA phases to land; this is NOT a per-phase drain.
#define SYNC_DRAIN() asm volatile("s_waitcnt vmcnt(0)\n\ts_barrier" ::: "memory")

// ---------------------------------------------------------------------------
// K0: fp32 -> bf16 pre-convert of latent_seasonal and w_seasonal.
// ---------------------------------------------------------------------------
__global__ __launch_bounds__(256)
void cvt_bf16(const float* __restrict__ ls, const float* __restrict__ wm,
              u16* __restrict__ lsb, u16* __restrict__ wmb)
{
    const size_t LSG = (size_t)B_DIM * N_SEQ * DM_DIM / 4;
    const size_t i = (size_t)blockIdx.x * 256 + threadIdx.x;
    const float* src;
    u16* dst;
    if (i < LSG) { src = ls + i * 4; dst = lsb + i * 4; }
    else         { const size_t j = i - LSG; src = wm + j * 4; dst = wmb + j * 4; }
    const f32x4 v = *(const f32x4*)src;
    u32* d = (u32*)dst;
    d[0] = cvtpk(v[0], v[1]);
    d[1] = cvtpk(v[2], v[3]);
}

// ---------------------------------------------------------------------------
// K1: 256x256 tile, BK=64, 8 waves (2M x 4N), per-wave output 128x64,
// mfma_f32_16x16x32_bf16, acc[8][4]. Deep-phase schedule (m201 template,
// race-free lead): per K-tile, 4 phases of {8 ds_read_b128 || stage-issue ||
// setprio(1) 16 MFMA setprio(0) || s_barrier}; tile t+1's 4 half-tiles
// (A-h0,A-h1 at phase0; W-h0,W-h1 at phase1) DMA'd into the clean buffer;
// ONE vmcnt(0)+barrier per K-tile (issued >=2 phases earlier -> hidden).
//
// LDS st_16x32 subtile swizzle: tile [128][64] stored as 8x2 subtiles of
// [16][32]; within subtile col ^= ((row>>3)&1)<<4. gload_lds dest is linear;
// the swizzle is applied via granule-inverse on the GLOBAL source address
// (rule #21); ds_read applies the same XOR.
// Epilogue: u = 2x - (acc+bias) (bf16) + per-chunk EMA end-values e (each
// wave owns one (chunk=wm, f-range=wn*64) -> shfl-only reduction).
// ---------------------------------------------------------------------------
__global__ __launch_bounds__(512, 2)
void gemm_u_kernel(const float* __restrict__ x,
                   const u16* __restrict__ lsb,
                   const u16* __restrict__ wmb,
                   const float* __restrict__ bias,
                   const float* __restrict__ alpha,
                   u16* __restrict__ u,
                   float* __restrict__ e)
{
    __shared__ u16 As[2][2][8192];  // [buf][half][128x64 swizzled]  64 KB
    __shared__ u16 Ws[2][2][8192];  //                               64 KB

    const int tid = threadIdx.x;

    // XCD remap: 2 f-siblings of each 512KB A-row-panel consecutive per XCD
    const int s  = blockIdx.x;                  // 0..511
    const int kk = s >> 3;                      // 0..63
    const int fb = kk & 1;                      // f-block 0..1
    const int rp = (s & 7) + ((kk >> 1) << 3);  // row-panel 0..255
    const int f0   = fb * 256;
    const int row0 = rp * 256;

    const int lane = tid & 63;
    const int wid  = tid >> 6;          // 0..7
    const int wm = wid >> 2;            // 0..1 (M half)
    const int wn = wid & 3;             // 0..3 (N quarter)
    const int wh = wn >> 1, wlo = wn & 1;
    const int l15 = lane & 15, l4 = lane >> 4;

    // --- staging granule decode (granule g, 16B): dest u16 = g*8.
    // inverse of idx(r,c) = ((r>>4)<<10)|((c>>5)<<9)|((r&15)<<5)|((c&31)^(((r>>3)&1)<<4))
    const int g0 = wid * 128 + lane;          // i = 0
    const int g1 = g0 + 64;                   // i = 1
    const int r0 = ((g0 >> 7) << 4) | ((g0 >> 2) & 15);
    const int c0 = (((g0 >> 6) & 1) << 5) | ((((g0 & 3) ^ (((g0 >> 5) & 1) << 1))) << 3);
    const int r1 = ((g1 >> 7) << 4) | ((g1 >> 2) & 15);
    const int c1 = (((g1 >> 6) & 1) << 5) | ((((g1 & 3) ^ (((g1 >> 5) & 1) << 1))) << 3);
    const int dst0 = wid * 1024;              // u16 offset in a half-buffer
    const int dst1 = wid * 1024 + 512;

    const u16* pa0 = lsb + (size_t)(row0 + r0) * DM_DIM + c0;
    const u16* pa1 = lsb + (size_t)(row0 + r1) * DM_DIM + c1;
    const u16* pw0 = wmb + (size_t)(f0 + r0) * DM_DIM + c0;
    const u16* pw1 = wmb + (size_t)(f0 + r1) * DM_DIM + c1;
    const size_t H = (size_t)128 * DM_DIM;    // half-tile row offset

    // --- fragment-read common offset (u16), same swizzle
    const int com = (l15 << 5) | ((l4 << 3) ^ (((l15 >> 3) & 1) << 4));

    f32x4 acc[8][4];
#pragma unroll
    for (int i = 0; i < 8; ++i)
#pragma unroll
        for (int j = 0; j < 4; ++j) acc[i][j] = (f32x4){0.f, 0.f, 0.f, 0.f};

#define STAGE_A(NB, T) do {                                               \
        gload16(pa0 + (size_t)(T) * 64,     &As[NB][0][dst0]);            \
        gload16(pa1 + (size_t)(T) * 64,     &As[NB][0][dst1]);            \
        gload16(pa0 + (size_t)(T) * 64 + H, &As[NB][1][dst0]);            \
        gload16(pa1 + (size_t)(T) * 64 + H, &As[NB][1][dst1]);            \
    } while (0)
#define STAGE_W(NB, T) do {                                               \
        gload16(pw0 + (size_t)(T) * 64,     &Ws[NB][0][dst0]);            \
        gload16(pw1 + (size_t)(T) * 64,     &Ws[NB][0][dst1]);            \
        gload16(pw0 + (size_t)(T) * 64 + H, &Ws[NB][1][dst0]);            \
        gload16(pw1 + (size_t)(T) * 64 + H, &Ws[NB][1][dst1]);            \
    } while (0)

#define PHASE(BUF, MIH, KS) do {                                          \
        const u16* _Ab = &As[BUF][wm][0];                                 \
        const u16* _Wb = &Ws[BUF][wh][0];                                 \
        bf16x8 _af[4], _wf[4];                                            \
        _Pragma("unroll")                                                 \
        for (int q = 0; q < 4; ++q)                                       \
            _af[q] = *(const bf16x8*)(_Ab + (((MIH)*4 + q) << 10)         \
                                          + ((KS) << 9) + com);           \
        _Pragma("unroll")                                                 \
        for (int n = 0; n < 4; ++n)                                       \
            _wf[n] = *(const bf16x8*)(_Wb + ((wlo*4 + n) << 10)           \
                                          + ((KS) << 9) + com);           \
        __builtin_amdgcn_s_setprio(1);                                    \
        _Pragma("unroll")                                                 \
        for (int q = 0; q < 4; ++q)                                       \
        _Pragma("unroll")                                                 \
        for (int n = 0; n < 4; ++n)                                       \
            acc[(MIH)*4 + q][n] = __builtin_amdgcn_mfma_f32_16x16x32_bf16(\
                _af[q], _wf[n], acc[(MIH)*4 + q][n], 0, 0, 0);            \
        __builtin_amdgcn_s_setprio(0);                                    \
    } while (0)

    // prologue: tile 0 fully staged into buf 0
    STAGE_A(0, 0);
    STAGE_W(0, 0);
    SYNC_DRAIN();

#pragma unroll 1
    for (int t = 0; t < NT; ++t) {
        const int bt = t & 1;
        const int nb = bt ^ 1;
        // phase 0: stage next A halves; compute mih=0, ks=0
        if (t + 1 < NT) STAGE_A(nb, t + 1);
        PHASE(bt, 0, 0);
        BAR();
        // phase 1: stage next W halves; compute mih=0, ks=1
        if (t + 1 < NT) STAGE_W(nb, t + 1);
        PHASE(bt, 0, 1);
        BAR();
        // phase 2: compute mih=1, ks=0
        PHASE(bt, 1, 0);
        BAR();
        // phase 3: compute mih=1, ks=1; then the tile's single drain
        PHASE(bt, 1, 1);
        SYNC_DRAIN();
    }

    // epilogue: u = 2x - (acc + bias) (bf16); chunk-end EMA.
    // Wave (wm,wn) owns chunk rp*2+wm, f-range [f0+wn*64, +64): shfl-only.
    const float a = 1.0f / (1.0f + expf(-alpha[0]));
    const float c = 1.0f - a;
    const float l2c = log2f(c);

    float bia[4];
#pragma unroll
    for (int ni = 0; ni < 4; ++ni) bia[ni] = bias[f0 + wn * 64 + ni * 16 + l15];

    float epart[4] = {0.f, 0.f, 0.f, 0.f};

#pragma unroll
    for (int mi = 0; mi < 8; ++mi) {
#pragma unroll
        for (int j = 0; j < 4; ++j) {
            const int rc = mi * 16 + l4 * 4 + j;            // row in chunk
            const int r  = wm * 128 + rc;                   // row in block
            const size_t rb = (size_t)(row0 + r) * TF_DIM;
            const float wgt = (rc == CHUNK - 1)
                                  ? a
                                  : a * exp2f((float)(CHUNK - 1 - rc) * l2c);
#pragma unroll
            for (int ni = 0; ni < 4; ++ni) {
                const int f = f0 + wn * 64 + ni * 16 + l15;
                const float uval = 2.0f * x[rb + f] - (acc[mi][ni][j] + bia[ni]);
                u[rb + f] = f2bf(uval);
                epart[ni] = fmaf(wgt, uval, epart[ni]);
            }
        }
    }

#pragma unroll
    for (int ni = 0; ni < 4; ++ni) {
        epart[ni] += __shfl_xor(epart[ni], 16, 64);
        epart[ni] += __shfl_xor(epart[ni], 32, 64);
    }
    if (l4 == 0) {
#pragma unroll
        for (int ni = 0; ni < 4; ++ni) {
            const int f = f0 + wn * 64 + ni * 16 + l15;
            e[(size_t)(rp * 2 + wm) * TF_DIM + f] = epart[ni];
        }
    }
}

// ---------------------------------------------------------------------------
// K3: serial carry scan over chunks per (b,f)
// ---------------------------------------------------------------------------
__global__ __launch_bounds__(256)
void ema_carry(const float* __restrict__ e, const float* __restrict__ alpha,
               float* __restrict__ carry)
{
    const int idx = blockIdx.x * 256 + threadIdx.x;  // b*TF + f
    const int f = idx & (TF_DIM - 1);
    const int b = idx >> 9;
    const float a = 1.0f / (1.0f + expf(-alpha[0]));
    const float c = 1.0f - a;
    const float cC = exp2f((float)CHUNK * log2f(c));  // c^CHUNK
    const size_t base = (size_t)b * NCHUNK * TF_DIM + f;
    float Y = 0.0f;
    carry[base] = 0.0f;
    for (int ch = 1; ch < NCHUNK; ++ch) {
        Y = fmaf(cC, Y, e[base + (size_t)(ch - 1) * TF_DIM]);
        carry[base + (size_t)ch * TF_DIM] = Y;
    }
}

// ---------------------------------------------------------------------------
// K4: apply chunk-local EMA with carry-in (u bf16, 2 cols/thread)
// ---------------------------------------------------------------------------
__global__ __launch_bounds__(256)
void ema_apply(const u16* __restrict__ u, const float* __restrict__ carry,
               const float* __restrict__ alpha, float* __restrict__ out)
{
    const int bc = blockIdx.x;                 // b*NCHUNK + ch, 0..511
    const int tid = threadIdx.x;               // owns f = 2*tid, 2*tid+1
    const float a = 1.0f / (1.0f + expf(-alpha[0]));
    const float c = 1.0f - a;
    float y0 = carry[(size_t)bc * TF_DIM + 2 * tid];
    float y1 = carry[(size_t)bc * TF_DIM + 2 * tid + 1];
    const u32* up = (const u32*)(u + (size_t)bc * CHUNK * TF_DIM) + tid;
    float2*    op = (float2*)(out + (size_t)bc * CHUNK * TF_DIM) + tid;
#pragma unroll 4
    for (int j = 0; j < CHUNK; ++j) {
        const u32 w = up[(size_t)j * (TF_DIM / 2)];
        const float u0 = __builtin_bit_cast(float, (w & 0xffffu) << 16);
        const float u1 = __builtin_bit_cast(float, (w >> 16) << 16);
        y0 = fmaf(c, y0, a * u0);
        y1 = fmaf(c, y1, a * u1);
        op[(size_t)j * (TF_DIM / 2)] = make_float2(y0, y1);
    }
}

extern "C" void kernel_launch(void* const* d_in, const int* in_sizes, int n_in,
                              void* d_out, int out_size, void* d_ws, size_t ws_size,
                              hipStream_t stream) {
    // setup_inputs order: x, latent_growth, latent_seasonal, alpha,
    //                     w_growth, b_growth, w_seasonal, b_seasonal
    const float* x     = (const float*)d_in[0];
    const float* ls    = (const float*)d_in[2];
    const float* alpha = (const float*)d_in[3];
    const float* wmat  = (const float*)d_in[6];
    const float* bias  = (const float*)d_in[7];
    float* out = (float*)d_out;

    // workspace layout (16B-aligned)
    u16*   u     = (u16*)d_ws;                                 // 67 MB bf16
    u16*   lsb   = u + (size_t)B_DIM * N_SEQ * TF_DIM;         // 134 MB bf16
    u16*   wmb   = lsb + (size_t)B_DIM * N_SEQ * DM_DIM;       // 1 MB bf16
    float* e     = (float*)(wmb + (size_t)TF_DIM * DM_DIM);    // 1 MB
    float* carry = e + (size_t)B_DIM * NCHUNK * TF_DIM;        // 1 MB

    // K0: fp32 -> bf16 conversion of ls + wmat
    const int cvt_blocks = (B_DIM * N_SEQ * DM_DIM / 4 + TF_DIM * DM_DIM / 4) / 256;
    cvt_bf16<<<cvt_blocks, 256, 0, stream>>>(ls, wmat, lsb, wmb);

    // K1: GEMM + u + chunk-end EMA  (512 blocks of 512 threads)
    gemm_u_kernel<<<512, 512, 0, stream>>>(x, lsb, wmb, bias, alpha, u, e);

    ema_carry<<<(B_DIM * TF_DIM) / 256, 256, 0, stream>>>(e, alpha, carry);
    ema_apply<<<B_DIM * NCHUNK, 256, 0, stream>>>(u, carry, alpha, out);
}